// Round 13
// baseline (171.058 us; speedup 1.0000x reference)
//
#include <hip/hip_runtime.h>
#include <hip/hip_bf16.h>

#define NREL 5000
#define NBIN 32
#define NEDGE 200000
#define DIM 512
#define NHEAD 8
#define PXLD 1536

typedef __attribute__((ext_vector_type(8))) short short8;
typedef __attribute__((ext_vector_type(4))) short short4v;
typedef __attribute__((ext_vector_type(4))) float f32x4;
typedef unsigned short ushort_t;

#define REL_N (NREL * DIM)
#define BIN_N (NBIN * DIM)
#define WATTN_N (DIM * 3 * DIM)
#define WAGGR_N (DIM * DIM)
#define CTOT (REL_N + BIN_N + WATTN_N + WAGGR_N)
#define CONV_BLOCKS (CTOT / 4 / 256)          // 4224, exact
#define COUNT_BLOCKS ((NEDGE + 255) / 256)    // 782

__device__ __forceinline__ float b2f(ushort_t u) {
  unsigned int v = ((unsigned int)u) << 16;
  union { unsigned int i; float f; } c; c.i = v; return c.f;
}
__device__ __forceinline__ ushort_t f2b_rne(float f) {
  union { float f; unsigned int u; } c; c.f = f;
  unsigned int u = c.u;
  return (ushort_t)((u + 0x7FFFu + ((u >> 16) & 1u)) >> 16);
}

// ---------- fused: convert 4 MFMA tensors f32->bf16  +  head count ----------
__global__ void conv_count_k(const float* __restrict__ s_rel, const float* __restrict__ s_bin,
                             const float* __restrict__ s_wattn, const float* __restrict__ s_waggr,
                             ushort_t* __restrict__ dst,
                             const int* __restrict__ trip, int* __restrict__ cnt) {
  int b = blockIdx.x;
  if (b < CONV_BLOCKS) {
    const int O1 = REL_N, O2 = O1 + BIN_N, O3 = O2 + WATTN_N;
    int i4 = (b * 256 + threadIdx.x) * 4;
    const float* src; int j;
    if (i4 < O1)      { src = s_rel;   j = i4; }
    else if (i4 < O2) { src = s_bin;   j = i4 - O1; }
    else if (i4 < O3) { src = s_wattn; j = i4 - O2; }
    else              { src = s_waggr; j = i4 - O3; }
    float4 v = *(const float4*)(src + j);
    short4v o;
    o[0] = (short)f2b_rne(v.x); o[1] = (short)f2b_rne(v.y);
    o[2] = (short)f2b_rne(v.z); o[3] = (short)f2b_rne(v.w);
    *(short4v*)(dst + i4) = o;
  } else {
    int e = (b - CONV_BLOCKS) * 256 + threadIdx.x;
    if (e >= NEDGE) return;
    int h = trip[3 * e];
    h = min(max(h, 0), NREL - 1);
    atomicAdd(&cnt[h], 1);
  }
}

// ---------- fast single-block exclusive scan over 5000 counts ----------
__global__ __launch_bounds__(256) void scan_k(const int* __restrict__ cnt, int* __restrict__ off) {
  __shared__ int wsum[4];
  int t = threadIdx.x, l = t & 63, w = t >> 6;
  int base = t * 20;
  int vals[20];
  int s = 0;
#pragma unroll
  for (int j = 0; j < 20; ++j) {
    int v = (base + j < NREL) ? cnt[base + j] : 0;
    vals[j] = s; s += v;
  }
  int x = s;
#pragma unroll
  for (int d = 1; d < 64; d <<= 1) {
    int y = __shfl_up(x, d, 64);
    if (l >= d) x += y;
  }
  if (l == 63) wsum[w] = x;
  __syncthreads();
  int woff = 0;
  for (int k = 0; k < 4; ++k) if (k < w) woff += wsum[k];
  int thr_excl = woff + x - s;
#pragma unroll
  for (int j = 0; j < 20; ++j)
    if (base + j < NREL) off[base + j] = thr_excl + vals[j];
  if (t == 255) off[NREL] = woff + x;
}

// ---------- scatter packed (tail_byteoff | bin<<24) into CSR slots ----------
__global__ void scatter_k(const int* __restrict__ src, const int* __restrict__ off,
                          int* __restrict__ cur, unsigned int* __restrict__ etb) {
  int e = blockIdx.x * 256 + threadIdx.x;
  if (e >= NEDGE) return;
  int h  = src[3 * e];
  int ta = src[3 * e + 1];
  int bi = src[3 * e + 2];
  h  = min(max(h, 0), NREL - 1);
  ta = min(max(ta, 0), NREL - 1);
  bi = min(max(bi, 0), NBIN - 1);
  int p = atomicAdd(&cur[h], 1);
  etb[off[h] + p] = (unsigned int)(ta * (PXLD * 2)) | ((unsigned int)bi << 24);
}

// ---------- LDS-staged (via registers) fused GEMM
//   PX[5000][1536] = (P1 | P3 | Mw+b_aggr), bf16
//   corner blocks bx==40 (by<4) -> P2[32][512] = emb_bin.W2^T + b_attn
__global__ __launch_bounds__(256) void gemm_fused(
    const ushort_t* __restrict__ c_rel, const ushort_t* __restrict__ c_bin,
    const ushort_t* __restrict__ c_wattn, const float* __restrict__ b_attn,
    const ushort_t* __restrict__ c_waggr, const float* __restrict__ b_aggr,
    ushort_t* __restrict__ PX, ushort_t* __restrict__ P2)
{
  __shared__ ushort_t Alds[128 * 32];
  __shared__ ushort_t Blds[128 * 32];
  int bx = blockIdx.x, by = blockIdx.y;
  const ushort_t* A; int Arows;
  const ushort_t* Bbase; int Bld; int joff;
  const float* bias;
  ushort_t* OUT; int OUTld;
  int rbase;
  if (bx == 40) {
    if (by >= 4) return;
    A = c_bin; Arows = NBIN; rbase = 0;
    Bbase = c_wattn + 512; Bld = 3 * DIM; joff = 0;
    bias = b_attn;
    OUT = P2; OUTld = DIM;
  } else {
    A = c_rel; Arows = NREL; rbase = bx * 128;
    int seg = by >> 2;
    if (seg == 2)      { Bbase = c_waggr;        Bld = DIM;     bias = b_aggr; }
    else if (seg == 1) { Bbase = c_wattn + 1024; Bld = 3 * DIM; bias = nullptr; }
    else               { Bbase = c_wattn;        Bld = 3 * DIM; bias = nullptr; }
    joff = seg * 512;
    OUT = PX; OUTld = PXLD;
  }
  int l = threadIdx.x & 63, wv = threadIdx.x >> 6;
  int wr = wv >> 1, wc = wv & 1;
  int ctb = by * 128;
  int r16 = l >> 2, sub = l & 3;
  int klo = (l >> 4) * 8;
  int ia0 = wv * 2, ia1 = wv * 2 + 1;
  int arow0 = min(rbase + ia0 * 16 + r16, Arows - 1);
  int arow1 = min(rbase + ia1 * 16 + r16, Arows - 1);
  int jloc0 = ctb + ia0 * 16 + r16 - joff;
  int jloc1 = ctb + ia1 * 16 + r16 - joff;
  const ushort_t* aSrc0 = A + (size_t)arow0 * DIM + sub * 8;
  const ushort_t* aSrc1 = A + (size_t)arow1 * DIM + sub * 8;
  const ushort_t* bSrc0 = Bbase + (size_t)jloc0 * Bld + sub * 8;
  const ushort_t* bSrc1 = Bbase + (size_t)jloc1 * Bld + sub * 8;
  ushort_t* aDst0 = Alds + ia0 * 512 + l * 8;
  ushort_t* aDst1 = Alds + ia1 * 512 + l * 8;
  ushort_t* bDst0 = Blds + ia0 * 512 + l * 8;
  ushort_t* bDst1 = Blds + ia1 * 512 + l * 8;

  f32x4 acc[4][4] = {};
  for (int kk = 0; kk < DIM; kk += 32) {
    short8 sa0 = *(const short8*)(aSrc0 + kk);
    short8 sa1 = *(const short8*)(aSrc1 + kk);
    short8 sb0 = *(const short8*)(bSrc0 + kk);
    short8 sb1 = *(const short8*)(bSrc1 + kk);
    if (kk) __syncthreads();
    *(short8*)aDst0 = sa0;
    *(short8*)aDst1 = sa1;
    *(short8*)bDst0 = sb0;
    *(short8*)bDst1 = sb1;
    __syncthreads();
    short8 aF[4], bF[4];
#pragma unroll
    for (int m2 = 0; m2 < 4; ++m2)
      aF[m2] = *(const short8*)(Alds + (wr * 64 + m2 * 16 + (l & 15)) * 32 + klo);
#pragma unroll
    for (int n = 0; n < 4; ++n)
      bF[n] = *(const short8*)(Blds + (wc * 64 + n * 16 + (l & 15)) * 32 + klo);
#pragma unroll
    for (int m2 = 0; m2 < 4; ++m2)
#pragma unroll
      for (int n = 0; n < 4; ++n)
        acc[m2][n] = __builtin_amdgcn_mfma_f32_16x16x32_bf16(aF[m2], bF[n], acc[m2][n], 0, 0, 0);
  }
  int r0 = rbase + wr * 64 + (l >> 4) * 4;
#pragma unroll
  for (int n = 0; n < 4; ++n) {
    int col = ctb + wc * 64 + n * 16 + (l & 15);
    float bv = bias ? bias[col - joff] : 0.0f;
#pragma unroll
    for (int m2 = 0; m2 < 4; ++m2) {
#pragma unroll
      for (int jj = 0; jj < 4; ++jj) {
        int row = r0 + m2 * 16 + jj;
        if (row < Arows) OUT[(size_t)row * OUTld + col] = f2b_rne(acc[m2][n][jj] + bv);
      }
    }
  }
}

// ---------- aggregation: 4 waves per relation, 1 relation per block ----------
// single-pass per-head online softmax with defer-max; byte-offset packed etb
__global__ __launch_bounds__(256, 8) void aggr4_k(
    const int* __restrict__ off, const unsigned int* __restrict__ etb,
    const ushort_t* __restrict__ PX, const ushort_t* __restrict__ P2,
    const float* __restrict__ avec, float* __restrict__ outf)
{
  __shared__ __align__(16) float red[4][DIM];
  __shared__ float ms[4][NHEAD][2];   // per-wave, per-head (m, s)

  int t = threadIdx.x;
  int l = t & 63, wv = t >> 6;
  int r = blockIdx.x;
  int off0 = off[r];
  int nE = off[r + 1] - off0;
  int q = nE >> 2, rem = nE & 3;
  int start = wv * q + min(wv, rem);
  int cnt = q + (wv < rem ? 1 : 0);

  int hd1 = l >> 3;                 // head owned by this 8-lane group
  int ob = hd1 * 64 + (l & 7) * 8;  // dim block for the logit dot

  float p1v[8], avv[8], avv02[8];
  {
    short8 p1b = *(const short8*)(PX + (size_t)r * PXLD + ob);
#pragma unroll
    for (int j = 0; j < 8; ++j) {
      p1v[j] = b2f((ushort_t)p1b[j]);
      float a = avec[ob + j];
      avv[j] = a;
      avv02[j] = 0.2f * a;
    }
  }
  float acc[8] = {};
  float m = -INFINITY, s = 0.0f;

  const char* P2c = (const char*)P2;
  const char* PXc = (const char*)PX;
  int ob2 = ob * 2;
  int l16 = l * 16;

  for (int ck = 0; ck < cnt; ck += 64) {
    int ne = min(64, cnt - ck);
    unsigned int tbreg = 0;
    if (l < ne) tbreg = etb[off0 + start + ck + l];
    for (int i = 0; i < ne; ++i) {
      unsigned int tb = (unsigned int)__shfl((int)tbreg, i);
      unsigned int boff = tb & 0x00FFFFFFu;       // tail * 3072 bytes
      unsigned int p2off = (tb >> 24) << 10;      // bin * 1024 bytes
      const char* pxrow = PXc + boff;
      short8 p2v = *(const short8*)(P2c + p2off + ob2);
      short8 p3v = *(const short8*)(pxrow + 1024 + ob2);
      short8 mv  = *(const short8*)(pxrow + 2048 + l16);
      float part = 0.0f;
#pragma unroll
      for (int j = 0; j < 8; ++j) {
        float z = p1v[j] + b2f((ushort_t)p2v[j]) + b2f((ushort_t)p3v[j]);
        part += z * (z > 0.f ? avv[j] : avv02[j]);
      }
      part += __shfl_xor(part, 1);
      part += __shfl_xor(part, 2);
      part += __shfl_xor(part, 4);   // per-head logit (uniform within 8-lane group)
      if (part > m + 8.0f) {         // defer-max rescale (group-uniform branch)
        float f = __expf(m - part);  // first edge: exp(-inf)=0
        s *= f;
#pragma unroll
        for (int j = 0; j < 8; ++j) acc[j] *= f;
        m = part;
      }
      float ev = __expf(part - m);
      s += ev;
#pragma unroll
      for (int j = 0; j < 8; ++j) acc[j] += ev * b2f((ushort_t)mv[j]);
    }
  }

  // ---- merge the four quarter-relation waves (one barrier) ----
#pragma unroll
  for (int j = 0; j < 8; ++j) red[wv][8 * l + j] = acc[j];
  if ((l & 7) == 0) { ms[wv][hd1][0] = m; ms[wv][hd1][1] = s; }
  __syncthreads();

  int d0 = t * 2;                   // 2 dims per thread (within one head)
  int h = d0 >> 6;
  float m0 = ms[0][h][0], m1 = ms[1][h][0], m2 = ms[2][h][0], m3 = ms[3][h][0];
  float M = fmaxf(fmaxf(m0, m1), fmaxf(m2, m3));
  float c0 = (m0 == M) ? 1.0f : __expf(m0 - M);
  float c1 = (m1 == M) ? 1.0f : __expf(m1 - M);
  float c2 = (m2 == M) ? 1.0f : __expf(m2 - M);
  float c3 = (m3 == M) ? 1.0f : __expf(m3 - M);
  float S = ms[0][h][1] * c0 + ms[1][h][1] * c1 + ms[2][h][1] * c2 + ms[3][h][1] * c3;
  float inv = 1.0f / (S + 1e-16f);
  float2 val;
  val.x = (red[0][d0] * c0 + red[1][d0] * c1 + red[2][d0] * c2 + red[3][d0] * c3) * inv;
  val.y = (red[0][d0 + 1] * c0 + red[1][d0 + 1] * c1 + red[2][d0 + 1] * c2 + red[3][d0 + 1] * c3) * inv;
  *(float2*)(outf + (size_t)r * DIM + d0) = val;
}

extern "C" void kernel_launch(void* const* d_in, const int* in_sizes, int n_in,
                              void* d_out, int out_size, void* d_ws, size_t ws_size,
                              hipStream_t stream) {
  const float* s_rel   = (const float*)d_in[0];
  const float* s_bin   = (const float*)d_in[1];
  const int*   trip    = (const int*)d_in[2];     // int32
  const float* s_wattn = (const float*)d_in[3];
  const float* b_attn  = (const float*)d_in[4];
  const float* avec    = (const float*)d_in[5];
  const float* s_waggr = (const float*)d_in[6];
  const float* b_aggr  = (const float*)d_in[7];

  ushort_t* canon = (ushort_t*)d_ws;
  ushort_t* c_rel   = canon;
  ushort_t* c_bin   = c_rel + REL_N;
  ushort_t* c_wattn = c_bin + BIN_N;
  ushort_t* c_waggr = c_wattn + WATTN_N;
  int* cnt = (int*)(c_waggr + WAGGR_N);
  int* cur = cnt + NREL;
  int* off = cur + NREL;                          // NREL+1
  unsigned int* etb = (unsigned int*)(off + NREL + 1);
  ushort_t* PX = (ushort_t*)(((uintptr_t)(etb + NEDGE) + 15) & ~(uintptr_t)15);
  ushort_t* P2 = PX + (size_t)NREL * PXLD;

  hipMemsetAsync(cnt, 0, 2 * NREL * sizeof(int), stream);  // cnt + cur

  conv_count_k<<<CONV_BLOCKS + COUNT_BLOCKS, 256, 0, stream>>>(
      s_rel, s_bin, s_wattn, s_waggr, canon, trip, cnt);
  scan_k<<<1, 256, 0, stream>>>(cnt, off);
  scatter_k<<<(NEDGE + 255) / 256, 256, 0, stream>>>(trip, off, cur, etb);

  dim3 gg(41, 12);
  gemm_fused<<<gg, 256, 0, stream>>>(c_rel, c_bin, c_wattn, b_attn, c_waggr, b_aggr,
                                     PX, P2);

  aggr4_k<<<NREL, 256, 0, stream>>>(off, etb, PX, P2, avec, (float*)d_out);
}

// Round 14
// 155.228 us; speedup vs baseline: 1.1020x; 1.1020x over previous
//
#include <hip/hip_runtime.h>
#include <hip/hip_bf16.h>

#define NREL 5000
#define NBIN 32
#define NEDGE 200000
#define DIM 512
#define NHEAD 8

typedef __attribute__((ext_vector_type(8))) short short8;
typedef __attribute__((ext_vector_type(4))) short short4v;
typedef __attribute__((ext_vector_type(4))) float f32x4;
typedef unsigned short ushort_t;

#define REL_N (NREL * DIM)
#define BIN_N (NBIN * DIM)
#define WATTN_N (DIM * 3 * DIM)
#define WAGGR_N (DIM * DIM)
#define CTOT (REL_N + BIN_N + WATTN_N + WAGGR_N)
#define CONV_BLOCKS (CTOT / 4 / 256)          // 3540, exact
#define COUNT_BLOCKS ((NEDGE + 255) / 256)    // 782

__device__ __forceinline__ float b2f(ushort_t u) {
  unsigned int v = ((unsigned int)u) << 16;
  union { unsigned int i; float f; } c; c.i = v; return c.f;
}
__device__ __forceinline__ ushort_t f2b_rne(float f) {
  union { float f; unsigned int u; } c; c.f = f;
  unsigned int u = c.u;
  return (ushort_t)((u + 0x7FFFu + ((u >> 16) & 1u)) >> 16);
}

// ---------- fused: convert 4 MFMA tensors f32->bf16  +  head count ----------
__global__ void conv_count_k(const float* __restrict__ s_rel, const float* __restrict__ s_bin,
                             const float* __restrict__ s_wattn, const float* __restrict__ s_waggr,
                             ushort_t* __restrict__ dst,
                             const int* __restrict__ trip, int* __restrict__ cnt) {
  int b = blockIdx.x;
  if (b < CONV_BLOCKS) {
    const int O1 = REL_N, O2 = O1 + BIN_N, O3 = O2 + WATTN_N;
    int i4 = (b * 256 + threadIdx.x) * 4;
    const float* src; int j;
    if (i4 < O1)      { src = s_rel;   j = i4; }
    else if (i4 < O2) { src = s_bin;   j = i4 - O1; }
    else if (i4 < O3) { src = s_wattn; j = i4 - O2; }
    else              { src = s_waggr; j = i4 - O3; }
    float4 v = *(const float4*)(src + j);
    short4v o;
    o[0] = (short)f2b_rne(v.x); o[1] = (short)f2b_rne(v.y);
    o[2] = (short)f2b_rne(v.z); o[3] = (short)f2b_rne(v.w);
    *(short4v*)(dst + i4) = o;
  } else {
    int e = (b - CONV_BLOCKS) * 256 + threadIdx.x;
    if (e >= NEDGE) return;
    int h = trip[3 * e];
    h = min(max(h, 0), NREL - 1);
    atomicAdd(&cnt[h], 1);
  }
}

// ---------- fast single-block exclusive scan over 5000 counts ----------
__global__ __launch_bounds__(256) void scan_k(const int* __restrict__ cnt, int* __restrict__ off) {
  __shared__ int wsum[4];
  int t = threadIdx.x, l = t & 63, w = t >> 6;
  int base = t * 20;
  int vals[20];
  int s = 0;
#pragma unroll
  for (int j = 0; j < 20; ++j) {
    int v = (base + j < NREL) ? cnt[base + j] : 0;
    vals[j] = s; s += v;
  }
  int x = s;
#pragma unroll
  for (int d = 1; d < 64; d <<= 1) {
    int y = __shfl_up(x, d, 64);
    if (l >= d) x += y;
  }
  if (l == 63) wsum[w] = x;
  __syncthreads();
  int woff = 0;
  for (int k = 0; k < 4; ++k) if (k < w) woff += wsum[k];
  int thr_excl = woff + x - s;
#pragma unroll
  for (int j = 0; j < 20; ++j)
    if (base + j < NREL) off[base + j] = thr_excl + vals[j];
  if (t == 255) off[NREL] = woff + x;
}

// ---------- scatter packed (tail*2048 | bin<<24) into CSR slots ----------
__global__ void scatter_k(const int* __restrict__ src, const int* __restrict__ off,
                          int* __restrict__ cur, unsigned int* __restrict__ etb) {
  int e = blockIdx.x * 256 + threadIdx.x;
  if (e >= NEDGE) return;
  int h  = src[3 * e];
  int ta = src[3 * e + 1];
  int bi = src[3 * e + 2];
  h  = min(max(h, 0), NREL - 1);
  ta = min(max(ta, 0), NREL - 1);
  bi = min(max(bi, 0), NBIN - 1);
  int p = atomicAdd(&cur[h], 1);
  etb[off[h] + p] = ((unsigned int)ta << 11) | ((unsigned int)bi << 24);
}

// ---------- LDS-staged (via registers) fused GEMM
//   P1B[5000][512] = P1; PM[5000][1024] = (P3 | Mw+b_aggr); all bf16
//   corner blocks bx==40 (by<4) -> P2[32][512] = emb_bin.W2^T + b_attn
__global__ __launch_bounds__(256) void gemm_fused(
    const ushort_t* __restrict__ c_rel, const ushort_t* __restrict__ c_bin,
    const ushort_t* __restrict__ c_wattn, const float* __restrict__ b_attn,
    const ushort_t* __restrict__ c_waggr, const float* __restrict__ b_aggr,
    ushort_t* __restrict__ P1B, ushort_t* __restrict__ PM, ushort_t* __restrict__ P2)
{
  __shared__ ushort_t Alds[128 * 32];
  __shared__ ushort_t Blds[128 * 32];
  int bx = blockIdx.x, by = blockIdx.y;
  const ushort_t* A; int Arows;
  const ushort_t* Bbase; int Bld; int joff;
  const float* bias;
  ushort_t* OUT; int OUTld; int ocolOff;
  int rbase;
  if (bx == 40) {
    if (by >= 4) return;
    A = c_bin; Arows = NBIN; rbase = 0;
    Bbase = c_wattn + 512; Bld = 3 * DIM; joff = 0;
    bias = b_attn;
    OUT = P2; OUTld = DIM; ocolOff = 0;
  } else {
    A = c_rel; Arows = NREL; rbase = bx * 128;
    int seg = by >> 2;
    if (seg == 2)      { Bbase = c_waggr;        Bld = DIM;     bias = b_aggr; }
    else if (seg == 1) { Bbase = c_wattn + 1024; Bld = 3 * DIM; bias = nullptr; }
    else               { Bbase = c_wattn;        Bld = 3 * DIM; bias = nullptr; }
    joff = seg * 512;
    OUT = (seg == 0) ? P1B : PM;
    OUTld = (seg == 0) ? DIM : 1024;
    ocolOff = (seg == 0) ? 0 : 512;     // seg1: col-512 -> [0,512); seg2: col-512 -> [512,1024)
  }
  int l = threadIdx.x & 63, wv = threadIdx.x >> 6;
  int wr = wv >> 1, wc = wv & 1;
  int ctb = by * 128;
  int r16 = l >> 2, sub = l & 3;
  int klo = (l >> 4) * 8;
  int ia0 = wv * 2, ia1 = wv * 2 + 1;
  int arow0 = min(rbase + ia0 * 16 + r16, Arows - 1);
  int arow1 = min(rbase + ia1 * 16 + r16, Arows - 1);
  int jloc0 = ctb + ia0 * 16 + r16 - joff;
  int jloc1 = ctb + ia1 * 16 + r16 - joff;
  const ushort_t* aSrc0 = A + (size_t)arow0 * DIM + sub * 8;
  const ushort_t* aSrc1 = A + (size_t)arow1 * DIM + sub * 8;
  const ushort_t* bSrc0 = Bbase + (size_t)jloc0 * Bld + sub * 8;
  const ushort_t* bSrc1 = Bbase + (size_t)jloc1 * Bld + sub * 8;
  ushort_t* aDst0 = Alds + ia0 * 512 + l * 8;
  ushort_t* aDst1 = Alds + ia1 * 512 + l * 8;
  ushort_t* bDst0 = Blds + ia0 * 512 + l * 8;
  ushort_t* bDst1 = Blds + ia1 * 512 + l * 8;

  f32x4 acc[4][4] = {};
  for (int kk = 0; kk < DIM; kk += 32) {
    short8 sa0 = *(const short8*)(aSrc0 + kk);
    short8 sa1 = *(const short8*)(aSrc1 + kk);
    short8 sb0 = *(const short8*)(bSrc0 + kk);
    short8 sb1 = *(const short8*)(bSrc1 + kk);
    if (kk) __syncthreads();
    *(short8*)aDst0 = sa0;
    *(short8*)aDst1 = sa1;
    *(short8*)bDst0 = sb0;
    *(short8*)bDst1 = sb1;
    __syncthreads();
    short8 aF[4], bF[4];
#pragma unroll
    for (int m2 = 0; m2 < 4; ++m2)
      aF[m2] = *(const short8*)(Alds + (wr * 64 + m2 * 16 + (l & 15)) * 32 + klo);
#pragma unroll
    for (int n = 0; n < 4; ++n)
      bF[n] = *(const short8*)(Blds + (wc * 64 + n * 16 + (l & 15)) * 32 + klo);
#pragma unroll
    for (int m2 = 0; m2 < 4; ++m2)
#pragma unroll
      for (int n = 0; n < 4; ++n)
        acc[m2][n] = __builtin_amdgcn_mfma_f32_16x16x32_bf16(aF[m2], bF[n], acc[m2][n], 0, 0, 0);
  }
  int r0 = rbase + wr * 64 + (l >> 4) * 4;
#pragma unroll
  for (int n = 0; n < 4; ++n) {
    int col = ctb + wc * 64 + n * 16 + (l & 15);
    float bv = bias ? bias[col - joff] : 0.0f;
    int ocol = col - ocolOff;
#pragma unroll
    for (int m2 = 0; m2 < 4; ++m2) {
#pragma unroll
      for (int jj = 0; jj < 4; ++jj) {
        int row = r0 + m2 * 16 + jj;
        if (row < Arows) OUT[(size_t)row * OUTld + ocol] = f2b_rne(acc[m2][n][jj] + bv);
      }
    }
  }
}

// ---------- aggregation: 2 waves per relation, 2 relations per block ----------
// single-pass per-head online softmax with defer-max; 2-deep edge pipeline
#define EDGE_LOAD(TB, P2V, P3V, MV)                                     \
  {                                                                     \
    const char* row_ = PMc + ((TB) & 0x00FFFFFFu);                      \
    P2V = *(const short8*)(P2c + (((TB) >> 24) << 10) + l16);           \
    P3V = *(const short8*)(row_ + l16);                                 \
    MV  = *(const short8*)(row_ + 1024 + l16);                          \
  }

#define EDGE_COMPUTE(P2V, P3V, MV)                                      \
  {                                                                     \
    float part = 0.0f;                                                  \
    _Pragma("unroll")                                                   \
    for (int j = 0; j < 8; ++j) {                                       \
      float z = p1v[j] + b2f((ushort_t)P2V[j]) + b2f((ushort_t)P3V[j]); \
      part += z * (z > 0.f ? avv[j] : avv02[j]);                        \
    }                                                                   \
    part += __shfl_xor(part, 1);                                        \
    part += __shfl_xor(part, 2);                                        \
    part += __shfl_xor(part, 4);                                        \
    if (part > m + 8.0f) {                                              \
      float f = __expf(m - part);                                       \
      s *= f;                                                           \
      _Pragma("unroll")                                                 \
      for (int j = 0; j < 8; ++j) acc[j] *= f;                          \
      m = part;                                                         \
    }                                                                   \
    float ev = __expf(part - m);                                        \
    s += ev;                                                            \
    _Pragma("unroll")                                                   \
    for (int j = 0; j < 8; ++j) acc[j] += ev * b2f((ushort_t)MV[j]);    \
  }

__global__ __launch_bounds__(256, 6) void aggr2_k(
    const int* __restrict__ off, const unsigned int* __restrict__ etb,
    const ushort_t* __restrict__ P1B, const ushort_t* __restrict__ PM,
    const ushort_t* __restrict__ P2, const float* __restrict__ avec,
    float* __restrict__ outf)
{
  __shared__ __align__(16) float red[4][DIM];
  __shared__ float ms[4][NHEAD][2];   // per-wave, per-head (m, s)

  int t = threadIdx.x;
  int l = t & 63, wv = t >> 6;
  int p = wv >> 1, sub = wv & 1;
  int r = blockIdx.x * 2 + p;
  int off0 = off[r];
  int nE = off[r + 1] - off0;
  int half = nE >> 1;
  int start = sub ? half : 0;
  int cnt = sub ? (nE - half) : half;

  int hd1 = l >> 3;                 // head owned by this 8-lane group
  int ob = hd1 * 64 + (l & 7) * 8;  // == 8*l (lane-linear)
  int l16 = l * 16;

  float p1v[8], avv[8], avv02[8];
  {
    short8 p1b = *(const short8*)(P1B + (size_t)r * DIM + ob);
#pragma unroll
    for (int j = 0; j < 8; ++j) {
      p1v[j] = b2f((ushort_t)p1b[j]);
      float a = avec[ob + j];
      avv[j] = a;
      avv02[j] = 0.2f * a;
    }
  }
  float acc[8] = {};
  float m = -INFINITY, s = 0.0f;

  const char* PMc = (const char*)PM;
  const char* P2c = (const char*)P2;

  for (int ck = 0; ck < cnt; ck += 64) {
    int ne = min(64, cnt - ck);
    unsigned int tbreg = 0;
    if (l < ne) tbreg = etb[off0 + start + ck + l];
    short8 p2A, p3A, mvA, p2B, p3B, mvB;
    unsigned int tb0 = (unsigned int)__shfl((int)tbreg, 0);
    EDGE_LOAD(tb0, p2A, p3A, mvA);
    int i = 0;
    while (i + 1 < ne) {
      unsigned int tbb = (unsigned int)__shfl((int)tbreg, i + 1);
      EDGE_LOAD(tbb, p2B, p3B, mvB);
      EDGE_COMPUTE(p2A, p3A, mvA);
      if (i + 2 < ne) {
        unsigned int tba = (unsigned int)__shfl((int)tbreg, i + 2);
        EDGE_LOAD(tba, p2A, p3A, mvA);
      }
      EDGE_COMPUTE(p2B, p3B, mvB);
      i += 2;
    }
    if (i < ne) EDGE_COMPUTE(p2A, p3A, mvA);
  }

  // ---- merge the two half-relation waves (one barrier) ----
#pragma unroll
  for (int j = 0; j < 8; ++j) red[wv][8 * l + j] = acc[j];
  if ((l & 7) == 0) { ms[wv][hd1][0] = m; ms[wv][hd1][1] = s; }
  __syncthreads();

  int pp = t >> 7;                  // relation within block
  int d0 = (t & 127) * 4;           // 4 dims per thread (within one head)
  int h = d0 >> 6;                  // head of these dims
  int rr = blockIdx.x * 2 + pp;
  float m1 = ms[2 * pp][h][0], s1 = ms[2 * pp][h][1];
  float m2 = ms[2 * pp + 1][h][0], s2 = ms[2 * pp + 1][h][1];
  float M = fmaxf(m1, m2);
  float c1 = (m1 == M) ? 1.0f : __expf(m1 - M);
  float c2 = (m2 == M) ? 1.0f : __expf(m2 - M);
  float S = s1 * c1 + s2 * c2;
  float inv = 1.0f / (S + 1e-16f);
  float4 val;
  val.x = (red[2 * pp][d0]     * c1 + red[2 * pp + 1][d0]     * c2) * inv;
  val.y = (red[2 * pp][d0 + 1] * c1 + red[2 * pp + 1][d0 + 1] * c2) * inv;
  val.z = (red[2 * pp][d0 + 2] * c1 + red[2 * pp + 1][d0 + 2] * c2) * inv;
  val.w = (red[2 * pp][d0 + 3] * c1 + red[2 * pp + 1][d0 + 3] * c2) * inv;
  *(float4*)(outf + (size_t)rr * DIM + d0) = val;
}

extern "C" void kernel_launch(void* const* d_in, const int* in_sizes, int n_in,
                              void* d_out, int out_size, void* d_ws, size_t ws_size,
                              hipStream_t stream) {
  const float* s_rel   = (const float*)d_in[0];
  const float* s_bin   = (const float*)d_in[1];
  const int*   trip    = (const int*)d_in[2];     // int32
  const float* s_wattn = (const float*)d_in[3];
  const float* b_attn  = (const float*)d_in[4];
  const float* avec    = (const float*)d_in[5];
  const float* s_waggr = (const float*)d_in[6];
  const float* b_aggr  = (const float*)d_in[7];

  ushort_t* canon = (ushort_t*)d_ws;
  ushort_t* c_rel   = canon;
  ushort_t* c_bin   = c_rel + REL_N;
  ushort_t* c_wattn = c_bin + BIN_N;
  ushort_t* c_waggr = c_wattn + WATTN_N;
  int* cnt = (int*)(c_waggr + WAGGR_N);
  int* cur = cnt + NREL;
  int* off = cur + NREL;                          // NREL+1
  unsigned int* etb = (unsigned int*)(off + NREL + 1);
  ushort_t* P1B = (ushort_t*)(((uintptr_t)(etb + NEDGE) + 15) & ~(uintptr_t)15);
  ushort_t* PM  = P1B + (size_t)NREL * DIM;       // 5000*1024 bf16, 16B-aligned
  ushort_t* P2  = PM + (size_t)NREL * 1024;       // 32*512 bf16

  hipMemsetAsync(cnt, 0, 2 * NREL * sizeof(int), stream);  // cnt + cur

  conv_count_k<<<CONV_BLOCKS + COUNT_BLOCKS, 256, 0, stream>>>(
      s_rel, s_bin, s_wattn, s_waggr, canon, trip, cnt);
  scan_k<<<1, 256, 0, stream>>>(cnt, off);
  scatter_k<<<(NEDGE + 255) / 256, 256, 0, stream>>>(trip, off, cur, etb);

  dim3 gg(41, 12);
  gemm_fused<<<gg, 256, 0, stream>>>(c_rel, c_bin, c_wattn, b_attn, c_waggr, b_aggr,
                                     P1B, PM, P2);

  aggr2_k<<<NREL / 2, 256, 0, stream>>>(off, etb, P1B, PM, P2, avec, (float*)d_out);
}